// Round 17
// baseline (261.721 us; speedup 1.0000x reference)
//
#include <hip/hip_runtime.h>
#include <hip/hip_bf16.h>
#include <math.h>

#define N_NODES 100000
#define N_EDGES 1600000
#define HEADS 8
#define HC 128
#define LOG2E 1.44269504f

#define DPB 64                    // dests per bucket
#define NB 1563                   // ceil(100000/64)
#define NBP (NB + 1)              // offsets rows (with end sentinel)
#define NCH 512                   // edge chunks (1.6M/512 = 3125 exact)
#define EPC (N_EDGES / NCH)       // 3125
#define CAPS 2048                 // per-bucket LDS cap (mean ~1088, max ~1300)
#define NA 196                    // amat-role blocks (196*512 >= 100000)

// ============ K1: fused a-matrix node pass + counting sort ===================
__global__ __launch_bounds__(512) void k_prep(
    const float* __restrict__ x, const float* __restrict__ W,
    const float* __restrict__ att_s, const float* __restrict__ att_d,
    const int* __restrict__ ei,
    unsigned short* __restrict__ a_srcb, float* __restrict__ a_dst,
    uint4* __restrict__ x2b,
    int* __restrict__ offs, unsigned* __restrict__ stg) {
    __shared__ int smem[2048 + EPC];     // csort: hist[2048]+entries; amat: sM
    __shared__ int ws8[8];
    int t = threadIdx.x;
    if (blockIdx.x >= NCH) {
        // ---- amat role ----
        float* sM = (float*)smem;        // [16][16]; h2<8 -> src, h2>=8 -> dst
        if (t < 256) {
            int k = t >> 4, h2 = t & 15;
            const float* av = (h2 < 8) ? att_s : att_d;
            int h = h2 & 7;
            float s = 0.f;
#pragma unroll
            for (int c = 0; c < 16; ++c)
                s = fmaf(W[k * HC + h * 16 + c], av[h * 16 + c], s);
            sM[k * 16 + h2] = s * LOG2E;
        }
        __syncthreads();
        int node = (blockIdx.x - NCH) * 512 + t;
        if (node < N_NODES) {
            const float4* xr = (const float4*)(x + node * 16);
            float4 x0 = xr[0], x1 = xr[1], x2 = xr[2], x3 = xr[3];
            float xv[16] = {x0.x, x0.y, x0.z, x0.w, x1.x, x1.y, x1.z, x1.w,
                            x2.x, x2.y, x2.z, x2.w, x3.x, x3.y, x3.z, x3.w};
            union { uint4 u[2]; __hip_bfloat162 b[8]; } px;
#pragma unroll
            for (int k = 0; k < 8; ++k)
                px.b[k] = __float22bfloat162_rn(float2{xv[2 * k], xv[2 * k + 1]});
            x2b[node * 2] = px.u[0];
            x2b[node * 2 + 1] = px.u[1];
#pragma unroll
            for (int h2 = 0; h2 < 16; ++h2) {
                float o = 0.f;
#pragma unroll
                for (int k = 0; k < 16; ++k) o = fmaf(xv[k], sM[k * 16 + h2], o);
                if (h2 < 8) a_srcb[node * 8 + h2] =
                    __bfloat16_as_ushort(__float2bfloat16(o));
                else        a_dst[node * 8 + (h2 - 8)] = o;
            }
        }
    } else {
        // ---- csort role: bucket-sort chunk edges, write offsets row ----
        int* hist = smem;
        unsigned* entries = (unsigned*)(smem + 2048);
        int c = blockIdx.x;
        hist[t] = 0; hist[t + 512] = 0; hist[t + 1024] = 0; hist[t + 1536] = 0;
        __syncthreads();
        int beg = c * EPC, end = beg + EPC;
        for (int e = beg + t; e < end; e += 512)
            atomicAdd(&hist[ei[N_EDGES + e] >> 6], 1);
        __syncthreads();
        int i0 = 4 * t;
        int v0 = hist[i0], v1 = hist[i0 + 1], v2 = hist[i0 + 2], v3 = hist[i0 + 3];
        int s1 = v0 + v1, s2 = s1 + v2, T = s2 + v3;
        int lane = t & 63, wv = t >> 6;
        int inc = T;
#pragma unroll
        for (int off = 1; off < 64; off <<= 1) {
            int y = __shfl_up(inc, off);
            if (lane >= off) inc += y;
        }
        if (lane == 63) ws8[wv] = inc;
        __syncthreads();
        int wbase = 0;
        for (int k = 0; k < wv; ++k) wbase += ws8[k];
        int e0 = wbase + inc - T;
        hist[i0] = e0; hist[i0 + 1] = e0 + v0;
        hist[i0 + 2] = e0 + s1; hist[i0 + 3] = e0 + s2;
        __syncthreads();
        int row = c * NBP;
        for (int b = t; b < NB; b += 512) offs[row + b] = hist[b];
        if (t == 0) offs[row + NB] = EPC;
        __syncthreads();
        for (int e = beg + t; e < end; e += 512) {
            int src = ei[e], dst = ei[N_EDGES + e];
            int pos = atomicAdd(&hist[dst >> 6], 1);
            entries[pos] = ((unsigned)(dst & 63) << 17) | (unsigned)src;
        }
        __syncthreads();
        unsigned* so = stg + beg;
        for (int i = t; i < EPC; i += 512) so[i] = entries[i];
    }
}

// ============ K2: transpose offs [NCH][NBP] -> offsT [NBP][NCH] ==============
__global__ __launch_bounds__(256) void k_tr(const int* __restrict__ offs,
                                            int* __restrict__ offsT) {
    __shared__ int tile[64][65];
    int b0 = (blockIdx.x >> 3) * 64;
    int c0 = (blockIdx.x & 7) * 64;
    int t = threadIdx.x;
    for (int i = t; i < 4096; i += 256) {
        int cc = i >> 6, bb = i & 63;
        int b = b0 + bb;
        tile[bb][cc] = (b < NBP) ? offs[(c0 + cc) * NBP + b] : 0;
    }
    __syncthreads();
    for (int i = t; i < 4096; i += 256) {
        int bb = i >> 6, cc = i & 63;
        int b = b0 + bb;
        if (b < NBP) offsT[b * NCH + c0 + cc] = tile[bb][cc];
    }
}

// ============ K3: gather — wave-per-dest, octet-edge-parallel ================
// Phase 6 layout: one 64-lane wave per dest; lane (o=lane>>3, p=lane&7):
// octet o takes edges beg+o, +8, ... for head p (16 channel accs in VGPRs).
// 8 edges in flight per wave, 1 exp2 per (edge,head) — no redundant math.
__global__ __launch_bounds__(512) void k_gather(
    const __hip_bfloat162* __restrict__ x2b,
    const unsigned short* __restrict__ a_srcb, const float* __restrict__ W,
    const float* __restrict__ a_dst,
    const int* __restrict__ offsT, const unsigned* __restrict__ stg,
    const float* __restrict__ bias, const float* __restrict__ fc_w,
    const float* __restrict__ fc_b, float* __restrict__ out) {
    __shared__ unsigned estage[CAPS];
    __shared__ int cstage[CAPS];
    __shared__ float sW[16 * HC];       // 8 KB
    __shared__ float sad[DPB * 8];      // staged a_dst (2 KB)
    __shared__ float sbias[HC];
    __shared__ float sfc[HC * 5];
    __shared__ int o0_s[NCH];
    __shared__ int myb_s[NCH + 1];
    __shared__ int hist[DPB];
    __shared__ int bs[DPB + 1];
    __shared__ int ws8[8];
    int b = blockIdx.x, t = threadIdx.x;
    int d0 = b * DPB;
    for (int i = t; i < 16 * HC; i += 512) sW[i] = W[i];
    if (t < HC) sbias[t] = bias[t];
    for (int i = t; i < HC * 5; i += 512) sfc[i] = fc_w[i];
    {
        int gd = d0 + (t >> 3);
        sad[t] = (gd < N_NODES) ? a_dst[gd * 8 + (t & 7)] : 0.f;
    }
    // phase 1: segment starts/lengths (512 chunks, all threads)
    int lane = t & 63, wv = t >> 6;
    {
        int o0 = offsT[b * NCH + t];
        int len = offsT[(b + 1) * NCH + t] - o0;
        o0_s[t] = o0;
        int inc = len;
#pragma unroll
        for (int off = 1; off < 64; off <<= 1) {
            int y = __shfl_up(inc, off);
            if (lane >= off) inc += y;
        }
        if (lane == 63) ws8[wv] = inc;
        __syncthreads();
        int wbase = 0;
        for (int k = 0; k < wv; ++k) wbase += ws8[k];
        myb_s[t] = wbase + inc - len;
        if (t == 511) myb_s[NCH] = wbase + inc;
    }
    if (t < DPB) hist[t] = (d0 + t < N_NODES) ? 1 : 0;   // self loop pre-count
    __syncthreads();
    int tot = myb_s[NCH];
    // phase 2+3: cooperative coalesced copy + dest histogram (merged)
    for (int i = t; i < tot; i += 512) {
        int lo = 0, hi = NCH - 1;
#pragma unroll
        for (int s = 0; s < 9; ++s) {
            int mid = (lo + hi + 1) >> 1;
            if (myb_s[mid] <= i) lo = mid; else hi = mid - 1;
        }
        unsigned u = stg[lo * EPC + o0_s[lo] + (i - myb_s[lo])];
        estage[i] = u;
        atomicAdd(&hist[u >> 17], 1);
    }
    __syncthreads();
    // phase 4: 64-scan, place self loops, init cursors
    if (t < 64) {
        int v = hist[t];
        int iv = v;
#pragma unroll
        for (int off = 1; off < 64; off <<= 1) {
            int y = __shfl_up(iv, off);
            if (t >= off) iv += y;
        }
        int excl = iv - v;
        bs[t] = excl;
        if (t == 63) bs[64] = iv;
        int gd = d0 + t;
        bool val = gd < N_NODES;
        if (val) cstage[excl] = gd;
        hist[t] = excl + (val ? 1 : 0);
    }
    __syncthreads();
    // phase 5: place edges dest-sorted
    for (int i = t; i < tot; i += 512) {
        unsigned u = estage[i];
        int pos = atomicAdd(&hist[u >> 17], 1);
        cstage[pos] = (int)(u & 0x1FFFF);
    }
    __syncthreads();
    // phase 6: wave-per-dest gather
    int o = lane >> 3, p = lane & 7;
    for (int l = wv * 8; l < wv * 8 + 8; ++l) {
        int gd = d0 + l;
        if (gd >= N_NODES) break;
        int beg = bs[l], end = bs[l + 1];
        float ad = sad[l * 8 + p];
        float A[16];
#pragma unroll
        for (int k = 0; k < 16; ++k) A[k] = 0.f;
        float wsum = 0.f;
        for (int j = beg + o; j < end; j += 8) {
            int src = cstage[j];
            float as = __bfloat162float(
                __ushort_as_bfloat16(a_srcb[src * 8 + p]));
            float e = as + ad;
            e = fmaxf(e, 0.2f * e);
            float w = exp2f(e);
            const uint4* xr = (const uint4*)x2b + (size_t)src * 2;
            union { uint4 u; __hip_bfloat162 bb[4]; } q0, q1;
            q0.u = xr[0]; q1.u = xr[1];
#pragma unroll
            for (int k = 0; k < 4; ++k) {
                float2 f0 = __bfloat1622float2(q0.bb[k]);
                float2 f1 = __bfloat1622float2(q1.bb[k]);
                A[2 * k]     = fmaf(w, f0.x, A[2 * k]);
                A[2 * k + 1] = fmaf(w, f0.y, A[2 * k + 1]);
                A[8 + 2 * k]     = fmaf(w, f1.x, A[8 + 2 * k]);
                A[8 + 2 * k + 1] = fmaf(w, f1.y, A[8 + 2 * k + 1]);
            }
            wsum += w;
        }
        // reduce across octets (lanes with same p): xor 8,16,32
#pragma unroll
        for (int m = 8; m <= 32; m <<= 1) {
#pragma unroll
            for (int k = 0; k < 16; ++k) A[k] += __shfl_xor(A[k], m);
            wsum += __shfl_xor(wsum, m);
        }
        float inv = 1.f / (wsum + 1e-16f);
#pragma unroll
        for (int k = 0; k < 16; ++k) A[k] *= inv;
        // epilogue: 2 output channels per lane (64 x 2 = 128)
        int c0 = p * 16 + o * 2;
        float ov0 = 0.f, ov1 = 0.f;
#pragma unroll
        for (int k = 0; k < 16; ++k) {
            ov0 = fmaf(A[k], sW[k * HC + c0], ov0);
            ov1 = fmaf(A[k], sW[k * HC + c0 + 1], ov1);
        }
        ov0 = fmaxf(ov0 + sbias[c0], 0.f);
        ov1 = fmaxf(ov1 + sbias[c0 + 1], 0.f);
        float pj[5];
#pragma unroll
        for (int j2 = 0; j2 < 5; ++j2)
            pj[j2] = ov0 * sfc[c0 * 5 + j2] + ov1 * sfc[(c0 + 1) * 5 + j2];
#pragma unroll
        for (int m = 1; m < 64; m <<= 1) {
#pragma unroll
            for (int j2 = 0; j2 < 5; ++j2) pj[j2] += __shfl_xor(pj[j2], m);
        }
        if (lane == 0) {
            float lg[5], mx = -1e30f;
#pragma unroll
            for (int j2 = 0; j2 < 5; ++j2) {
                lg[j2] = pj[j2] + fc_b[j2];
                mx = fmaxf(mx, lg[j2]);
            }
            float sum = 0.f;
#pragma unroll
            for (int j2 = 0; j2 < 5; ++j2) sum += __expf(lg[j2] - mx);
            float ls = mx + __logf(sum);
#pragma unroll
            for (int j2 = 0; j2 < 5; ++j2) out[gd * 5 + j2] = lg[j2] - ls;
        }
    }
}

extern "C" void kernel_launch(void* const* d_in, const int* in_sizes, int n_in,
                              void* d_out, int out_size, void* d_ws, size_t ws_size,
                              hipStream_t stream) {
    const float* x     = (const float*)d_in[0];
    const int*   ei    = (const int*)d_in[1];
    const float* W     = (const float*)d_in[2];
    const float* att_s = (const float*)d_in[3];
    const float* att_d = (const float*)d_in[4];
    const float* bias  = (const float*)d_in[5];
    const float* fc_w  = (const float*)d_in[6];
    const float* fc_b  = (const float*)d_in[7];
    float* out = (float*)d_out;

    char* ws = (char*)d_ws;
    size_t off = 0;
    auto carve = [&](size_t bytes) {
        void* p = ws + off;
        off = (off + bytes + 255) & ~(size_t)255;
        return p;
    };
    unsigned short* a_srcb = (unsigned short*)carve((size_t)N_NODES * HEADS * 2);
    float*    a_dst = (float*)   carve((size_t)N_NODES * HEADS * 4);
    uint4*    x2b   = (uint4*)   carve((size_t)N_NODES * 32);
    int*      offs  = (int*)     carve((size_t)NCH * NBP * 4);
    int*      offsT = (int*)     carve((size_t)NBP * NCH * 4);
    unsigned* stg   = (unsigned*)carve((size_t)N_EDGES * 4);

    k_prep<<<NCH + NA, 512, 0, stream>>>(x, W, att_s, att_d, ei,
                                         a_srcb, a_dst, x2b, offs, stg);
    k_tr<<<200, 256, 0, stream>>>(offs, offsT);
    k_gather<<<NB, 512, 0, stream>>>((const __hip_bfloat162*)x2b, a_srcb, W,
                                     a_dst, offsT, stg, bias, fc_w, fc_b, out);
}

// Round 18
// 182.337 us; speedup vs baseline: 1.4354x; 1.4354x over previous
//
#include <hip/hip_runtime.h>
#include <hip/hip_bf16.h>
#include <math.h>

#define N_NODES 100000
#define N_EDGES 1600000
#define HEADS 8
#define HC 128
#define LOG2E 1.44269504f

#define DPB 64                    // dests per bucket
#define NB 1563                   // ceil(100000/64)
#define NBP (NB + 1)              // offsets rows (with end sentinel)
#define NCH 512                   // edge chunks (1.6M/512 = 3125 exact)
#define EPC (N_EDGES / NCH)       // 3125
#define CAPS 2048                 // per-bucket LDS cap (mean ~1088, max ~1300)
#define NA 196                    // amat-role blocks (196*512 >= 100000)

// ============ K1: fused a-matrix node pass + counting sort ===================
// csort role (blocks 0..NCH): LDS counting-sort 3125 edges by 64-dest bucket.
// amat role (blocks NCH..NCH+NA): a_src(bf16)/a_dst(f32) = x@M (M=W·att,
//   LOG2E folded) + x2b = bf16(x). Gather working set 4.8 MB ~ L2.
__global__ __launch_bounds__(512) void k_prep(
    const float* __restrict__ x, const float* __restrict__ W,
    const float* __restrict__ att_s, const float* __restrict__ att_d,
    const int* __restrict__ ei,
    unsigned short* __restrict__ a_srcb, float* __restrict__ a_dst,
    uint4* __restrict__ x2b,
    int* __restrict__ offs, unsigned* __restrict__ stg) {
    __shared__ int smem[2048 + EPC];     // csort: hist[2048]+entries; amat: sM
    __shared__ int ws8[8];
    int t = threadIdx.x;
    if (blockIdx.x >= NCH) {
        // ---- amat role ----
        float* sM = (float*)smem;        // [16][16]; h2<8 -> src, h2>=8 -> dst
        if (t < 256) {
            int k = t >> 4, h2 = t & 15;
            const float* av = (h2 < 8) ? att_s : att_d;
            int h = h2 & 7;
            float s = 0.f;
#pragma unroll
            for (int c = 0; c < 16; ++c)
                s = fmaf(W[k * HC + h * 16 + c], av[h * 16 + c], s);
            sM[k * 16 + h2] = s * LOG2E;
        }
        __syncthreads();
        int node = (blockIdx.x - NCH) * 512 + t;
        if (node < N_NODES) {
            const float4* xr = (const float4*)(x + node * 16);
            float4 x0 = xr[0], x1 = xr[1], x2 = xr[2], x3 = xr[3];
            float xv[16] = {x0.x, x0.y, x0.z, x0.w, x1.x, x1.y, x1.z, x1.w,
                            x2.x, x2.y, x2.z, x2.w, x3.x, x3.y, x3.z, x3.w};
            union { uint4 u[2]; __hip_bfloat162 b[8]; } px;
#pragma unroll
            for (int k = 0; k < 8; ++k)
                px.b[k] = __float22bfloat162_rn(float2{xv[2 * k], xv[2 * k + 1]});
            x2b[node * 2] = px.u[0];
            x2b[node * 2 + 1] = px.u[1];
#pragma unroll
            for (int h2 = 0; h2 < 16; ++h2) {
                float o = 0.f;
#pragma unroll
                for (int k = 0; k < 16; ++k) o = fmaf(xv[k], sM[k * 16 + h2], o);
                if (h2 < 8) a_srcb[node * 8 + h2] =
                    __bfloat16_as_ushort(__float2bfloat16(o));
                else        a_dst[node * 8 + (h2 - 8)] = o;
            }
        }
    } else {
        // ---- csort role: bucket-sort chunk edges, write offsets row ----
        int* hist = smem;
        unsigned* entries = (unsigned*)(smem + 2048);
        int c = blockIdx.x;
        hist[t] = 0; hist[t + 512] = 0; hist[t + 1024] = 0; hist[t + 1536] = 0;
        __syncthreads();
        int beg = c * EPC, end = beg + EPC;
        for (int e = beg + t; e < end; e += 512)
            atomicAdd(&hist[ei[N_EDGES + e] >> 6], 1);
        __syncthreads();
        int i0 = 4 * t;
        int v0 = hist[i0], v1 = hist[i0 + 1], v2 = hist[i0 + 2], v3 = hist[i0 + 3];
        int s1 = v0 + v1, s2 = s1 + v2, T = s2 + v3;
        int lane = t & 63, wv = t >> 6;
        int inc = T;
#pragma unroll
        for (int off = 1; off < 64; off <<= 1) {
            int y = __shfl_up(inc, off);
            if (lane >= off) inc += y;
        }
        if (lane == 63) ws8[wv] = inc;
        __syncthreads();
        int wbase = 0;
        for (int k = 0; k < wv; ++k) wbase += ws8[k];
        int e0 = wbase + inc - T;
        hist[i0] = e0; hist[i0 + 1] = e0 + v0;
        hist[i0 + 2] = e0 + s1; hist[i0 + 3] = e0 + s2;
        __syncthreads();
        int row = c * NBP;
        for (int b = t; b < NB; b += 512) offs[row + b] = hist[b];
        if (t == 0) offs[row + NB] = EPC;
        __syncthreads();
        for (int e = beg + t; e < end; e += 512) {
            int src = ei[e], dst = ei[N_EDGES + e];
            int pos = atomicAdd(&hist[dst >> 6], 1);
            entries[pos] = ((unsigned)(dst & 63) << 17) | (unsigned)src;
        }
        __syncthreads();
        unsigned* so = stg + beg;
        for (int i = t; i < EPC; i += 512) so[i] = entries[i];
    }
}

// ============ K2: transpose offs [NCH][NBP] -> offsT [NBP][NCH] ==============
__global__ __launch_bounds__(256) void k_tr(const int* __restrict__ offs,
                                            int* __restrict__ offsT) {
    __shared__ int tile[64][65];
    int b0 = (blockIdx.x >> 3) * 64;      // 25 b-tiles
    int c0 = (blockIdx.x & 7) * 64;       // 8 c-tiles
    int t = threadIdx.x;
    for (int i = t; i < 4096; i += 256) {
        int cc = i >> 6, bb = i & 63;
        int b = b0 + bb;
        tile[bb][cc] = (b < NBP) ? offs[(c0 + cc) * NBP + b] : 0;
    }
    __syncthreads();
    for (int i = t; i < 4096; i += 256) {
        int bb = i >> 6, cc = i & 63;
        int b = b0 + bb;
        if (b < NBP) offsT[b * NCH + c0 + cc] = tile[bb][cc];
    }
}

// ============ K3: gather in bf16 x-space -> @W epilogue -> FC -> softmax =====
__global__ __launch_bounds__(512) void k_gather(
    const __hip_bfloat162* __restrict__ x2b,
    const unsigned short* __restrict__ a_srcb, const float* __restrict__ W,
    const float* __restrict__ a_dst,
    const int* __restrict__ offsT, const unsigned* __restrict__ stg,
    const float* __restrict__ bias, const float* __restrict__ fc_w,
    const float* __restrict__ fc_b, float* __restrict__ out) {
    __shared__ unsigned estage[CAPS];
    __shared__ int cstage[CAPS];
    __shared__ float sW[16 * HC];
    __shared__ int o0_s[NCH];
    __shared__ int myb_s[NCH + 1];
    __shared__ int hist[DPB];
    __shared__ int bs[DPB + 1];
    __shared__ int ws8[8];
    int b = blockIdx.x, t = threadIdx.x;
    int d0 = b * DPB;
    for (int i = t; i < 16 * HC; i += 512) sW[i] = W[i];
    // phase 1: segment starts/lengths (512 chunks, all threads)
    int lane = t & 63, wv = t >> 6;
    {
        int o0 = offsT[b * NCH + t];
        int len = offsT[(b + 1) * NCH + t] - o0;
        o0_s[t] = o0;
        int inc = len;
#pragma unroll
        for (int off = 1; off < 64; off <<= 1) {
            int y = __shfl_up(inc, off);
            if (lane >= off) inc += y;
        }
        if (lane == 63) ws8[wv] = inc;
        __syncthreads();
        int wbase = 0;
        for (int k = 0; k < wv; ++k) wbase += ws8[k];
        myb_s[t] = wbase + inc - len;
        if (t == 511) myb_s[NCH] = wbase + inc;
    }
    if (t < DPB) hist[t] = (d0 + t < N_NODES) ? 1 : 0;   // self loop pre-count
    __syncthreads();
    int tot = myb_s[NCH];
    // phase 2: cooperative coalesced copy (binary search chunk per entry)
    for (int i = t; i < tot; i += 512) {
        int lo = 0, hi = NCH - 1;
#pragma unroll
        for (int s = 0; s < 9; ++s) {
            int mid = (lo + hi + 1) >> 1;
            if (myb_s[mid] <= i) lo = mid; else hi = mid - 1;
        }
        estage[i] = stg[lo * EPC + o0_s[lo] + (i - myb_s[lo])];
    }
    __syncthreads();
    // phase 3: dest histogram
    for (int i = t; i < tot; i += 512) atomicAdd(&hist[estage[i] >> 17], 1);
    __syncthreads();
    // phase 4: 64-scan, place self loops, init cursors
    if (t < 64) {
        int v = hist[t];
        int iv = v;
#pragma unroll
        for (int off = 1; off < 64; off <<= 1) {
            int y = __shfl_up(iv, off);
            if (t >= off) iv += y;
        }
        int excl = iv - v;
        bs[t] = excl;
        if (t == 63) bs[64] = iv;
        int gd = d0 + t;
        bool val = gd < N_NODES;
        if (val) cstage[excl] = gd;
        hist[t] = excl + (val ? 1 : 0);
    }
    __syncthreads();
    // phase 5: place edges dest-sorted
    for (int i = t; i < tot; i += 512) {
        unsigned u = estage[i];
        int pos = atomicAdd(&hist[u >> 17], 1);
        cstage[pos] = (int)(u & 0x1FFFF);
    }
    __syncthreads();
    // phase 6: x-space gather (unrolled x2 for MLP) + @W + FC + log_softmax
    int q = t & 31, g = t >> 5;
    int head = q >> 2, i4 = q & 3;
    int c0 = q * 4;               // output channels head*16 + i4*4
    float b0 = bias[c0], b1 = bias[c0 + 1], b2 = bias[c0 + 2], b3 = bias[c0 + 3];
    float fw[4][5], fb[5];
#pragma unroll
    for (int k = 0; k < 4; ++k)
#pragma unroll
        for (int j = 0; j < 5; ++j) fw[k][j] = fc_w[(c0 + k) * 5 + j];
#pragma unroll
    for (int j = 0; j < 5; ++j) fb[j] = fc_b[j];
    for (int l4 = 0; l4 < 4; ++l4) {
        int l = g * 4 + l4;
        int gd = d0 + l;
        if (gd >= N_NODES) break;
        int beg = bs[l], end = bs[l + 1];
        float ad = a_dst[gd * 8 + head];
        float A0 = 0.f, A1 = 0.f, A2 = 0.f, A3 = 0.f, wsum = 0.f;
        int j = beg;
        for (; j + 2 <= end; j += 2) {
            int s0 = cstage[j], s1 = cstage[j + 1];
            unsigned short u0 = a_srcb[s0 * 8 + head];
            unsigned short u1 = a_srcb[s1 * 8 + head];
            union { uint2 u; __hip_bfloat162 bb[2]; } xa, xb;
            xa.u = *(const uint2*)(x2b + (size_t)s0 * 8 + i4 * 2);
            xb.u = *(const uint2*)(x2b + (size_t)s1 * 8 + i4 * 2);
            float e0 = __bfloat162float(__ushort_as_bfloat16(u0)) + ad;
            float e1 = __bfloat162float(__ushort_as_bfloat16(u1)) + ad;
            e0 = fmaxf(e0, 0.2f * e0);
            e1 = fmaxf(e1, 0.2f * e1);
            float w0 = exp2f(e0), w1 = exp2f(e1);
            float2 a01 = __bfloat1622float2(xa.bb[0]);
            float2 a23 = __bfloat1622float2(xa.bb[1]);
            float2 b01 = __bfloat1622float2(xb.bb[0]);
            float2 b23 = __bfloat1622float2(xb.bb[1]);
            A0 = fmaf(w0, a01.x, A0); A1 = fmaf(w0, a01.y, A1);
            A2 = fmaf(w0, a23.x, A2); A3 = fmaf(w0, a23.y, A3);
            A0 = fmaf(w1, b01.x, A0); A1 = fmaf(w1, b01.y, A1);
            A2 = fmaf(w1, b23.x, A2); A3 = fmaf(w1, b23.y, A3);
            wsum += w0 + w1;
        }
        if (j < end) {
            int s0 = cstage[j];
            float as = __bfloat162float(
                __ushort_as_bfloat16(a_srcb[s0 * 8 + head]));
            float e = as + ad;
            e = fmaxf(e, 0.2f * e);
            float w = exp2f(e);
            union { uint2 u; __hip_bfloat162 bb[2]; } xu;
            xu.u = *(const uint2*)(x2b + (size_t)s0 * 8 + i4 * 2);
            float2 f01 = __bfloat1622float2(xu.bb[0]);
            float2 f23 = __bfloat1622float2(xu.bb[1]);
            A0 = fmaf(w, f01.x, A0); A1 = fmaf(w, f01.y, A1);
            A2 = fmaf(w, f23.x, A2); A3 = fmaf(w, f23.y, A3);
            wsum += w;
        }
        float inv = 1.f / (wsum + 1e-16f);
        A0 *= inv; A1 *= inv; A2 *= inv; A3 *= inv;
        // exchange x-space accs across the head's 4 lanes; apply W columns
        float ov0 = 0.f, ov1 = 0.f, ov2 = 0.f, ov3 = 0.f;
#pragma unroll
        for (int ii = 0; ii < 4; ++ii) {
            int sl = (q & 28) + ii;
            float a0 = __shfl(A0, sl, 32);
            float a1 = __shfl(A1, sl, 32);
            float a2 = __shfl(A2, sl, 32);
            float a3 = __shfl(A3, sl, 32);
            const float* w0 = sW + (4 * ii) * HC + c0;
            ov0 = fmaf(a0, w0[0], ov0); ov1 = fmaf(a0, w0[1], ov1);
            ov2 = fmaf(a0, w0[2], ov2); ov3 = fmaf(a0, w0[3], ov3);
            const float* w1 = w0 + HC;
            ov0 = fmaf(a1, w1[0], ov0); ov1 = fmaf(a1, w1[1], ov1);
            ov2 = fmaf(a1, w1[2], ov2); ov3 = fmaf(a1, w1[3], ov3);
            const float* w2 = w1 + HC;
            ov0 = fmaf(a2, w2[0], ov0); ov1 = fmaf(a2, w2[1], ov1);
            ov2 = fmaf(a2, w2[2], ov2); ov3 = fmaf(a2, w2[3], ov3);
            const float* w3 = w2 + HC;
            ov0 = fmaf(a3, w3[0], ov0); ov1 = fmaf(a3, w3[1], ov1);
            ov2 = fmaf(a3, w3[2], ov2); ov3 = fmaf(a3, w3[3], ov3);
        }
        ov0 = fmaxf(ov0 + b0, 0.f);
        ov1 = fmaxf(ov1 + b1, 0.f);
        ov2 = fmaxf(ov2 + b2, 0.f);
        ov3 = fmaxf(ov3 + b3, 0.f);
        float p[5];
#pragma unroll
        for (int j2 = 0; j2 < 5; ++j2)
            p[j2] = ov0 * fw[0][j2] + ov1 * fw[1][j2]
                  + ov2 * fw[2][j2] + ov3 * fw[3][j2];
#pragma unroll
        for (int off = 16; off >= 1; off >>= 1) {
#pragma unroll
            for (int j2 = 0; j2 < 5; ++j2) p[j2] += __shfl_xor(p[j2], off);
        }
        if (q == 0) {
            float lg[5], m = -1e30f;
#pragma unroll
            for (int j2 = 0; j2 < 5; ++j2) {
                lg[j2] = p[j2] + fb[j2];
                m = fmaxf(m, lg[j2]);
            }
            float sum = 0.f;
#pragma unroll
            for (int j2 = 0; j2 < 5; ++j2) sum += __expf(lg[j2] - m);
            float ls = m + __logf(sum);
#pragma unroll
            for (int j2 = 0; j2 < 5; ++j2) out[gd * 5 + j2] = lg[j2] - ls;
        }
    }
}

extern "C" void kernel_launch(void* const* d_in, const int* in_sizes, int n_in,
                              void* d_out, int out_size, void* d_ws, size_t ws_size,
                              hipStream_t stream) {
    const float* x     = (const float*)d_in[0];
    const int*   ei    = (const int*)d_in[1];
    const float* W     = (const float*)d_in[2];
    const float* att_s = (const float*)d_in[3];
    const float* att_d = (const float*)d_in[4];
    const float* bias  = (const float*)d_in[5];
    const float* fc_w  = (const float*)d_in[6];
    const float* fc_b  = (const float*)d_in[7];
    float* out = (float*)d_out;

    char* ws = (char*)d_ws;
    size_t off = 0;
    auto carve = [&](size_t bytes) {
        void* p = ws + off;
        off = (off + bytes + 255) & ~(size_t)255;
        return p;
    };
    unsigned short* a_srcb = (unsigned short*)carve((size_t)N_NODES * HEADS * 2);
    float*    a_dst = (float*)   carve((size_t)N_NODES * HEADS * 4);
    uint4*    x2b   = (uint4*)   carve((size_t)N_NODES * 32);
    int*      offs  = (int*)     carve((size_t)NCH * NBP * 4);
    int*      offsT = (int*)     carve((size_t)NBP * NCH * 4);
    unsigned* stg   = (unsigned*)carve((size_t)N_EDGES * 4);

    k_prep<<<NCH + NA, 512, 0, stream>>>(x, W, att_s, att_d, ei,
                                         a_srcb, a_dst, x2b, offs, stg);
    k_tr<<<200, 256, 0, stream>>>(offs, offsT);
    k_gather<<<NB, 512, 0, stream>>>((const __hip_bfloat162*)x2b, a_srcb, W,
                                     a_dst, offsT, stg, bias, fc_w, fc_b, out);
}